// Round 3
// baseline (98.438 us; speedup 1.0000x reference)
//
#include <hip/hip_runtime.h>

// out[s,d,b,j] = log( sum_i exp(x[s,d,b,i]) * acc[s,d,i,j] ) - log( sum_i acc[s,d,i,j] )
// 256 batched 256x256x256 GEMMs in linear space, bf16 MFMA, fp32 accumulate.
// Grid 512: block = (sd = bid&255, bhalf = bid>>8). b-split: x reads disjoint,
// acc slab shared via same-XCD L2 pairing, output writes full contiguous rows.

#define NSC 32
#define NDC 8
#define NB  256
#define NI  256
#define NJ  256
#define BH  128   // batch rows per block

typedef __attribute__((ext_vector_type(8))) short bf16x8;
typedef __attribute__((ext_vector_type(4))) float f32x4;

__device__ __forceinline__ unsigned short f2bf(float f) {
  unsigned int u = __float_as_uint(f);
  u += 0x7FFFu + ((u >> 16) & 1u);
  return (unsigned short)(u >> 16);
}

__global__ __launch_bounds__(512, 4)
void densesum_kernel(const float* __restrict__ x,
                     const float* __restrict__ acc,
                     float* __restrict__ out) {
  const int bid = blockIdx.x;
  const int sd  = bid & 255;                 // pair (sd, sd+256) -> same XCD
  const int bh  = bid >> 8;                  // 0/1: which 128-row batch half
  const float* xb = x   + (size_t)sd * NB * NI + (size_t)bh * BH * NI;
  const float* ab = acc + (size_t)sd * NI * NJ;
  float*       ob = out + (size_t)sd * NB * NJ + (size_t)bh * BH * NJ;

  // A = exp(x) [128 b][64 k] bf16 ; B^T = acc^T [256 j][64 k] bf16.
  // 128B rows, XOR swizzle elem ^= ((row&7)<<3) -> conflict-free ds_read_b128.
  __shared__ unsigned short As[BH * 64];
  __shared__ unsigned short Bs[NJ * 64];
  __shared__ float colpart[8 * NJ];
  __shared__ float logS[NJ];

  const int tid  = threadIdx.x;
  const int lane = tid & 63;
  const int wid  = tid >> 6;      // 8 waves
  const int wr   = wid >> 2;      // 0..1  (64-row strip of local b)
  const int wc   = wid & 3;       // 0..3  (64-col strip of j)
  const int l15  = lane & 15;
  const int lk   = lane >> 4;     // 0..3
  const int r    = (lane >> 1) & 3;   // write-order rotation
  const bool s1 = (r & 1), s2 = (r & 2);

  f32x4 C[4][4];
  #pragma unroll
  for (int m = 0; m < 4; ++m)
    #pragma unroll
    for (int n = 0; n < 4; ++n)
      C[m][n] = (f32x4){0.f, 0.f, 0.f, 0.f};

  float bsum0 = 0.f, bsum1 = 0.f, bsum2 = 0.f, bsum3 = 0.f;

  for (int kc = 0; kc < 4; ++kc) {
    const int i0 = kc * 64;

    // ---- stage A: exp(x) -> bf16, [b][k] swizzled (4 float4 / thread)
    #pragma unroll
    for (int it = 0; it < 4; ++it) {
      int q  = tid + it * 512;              // 0..2047 quads
      int b  = q >> 4;                      // 0..127
      int c0 = (q & 15) * 4;                // 0..60
      const float4 xv = *reinterpret_cast<const float4*>(xb + (size_t)b * NI + i0 + c0);
      ushort4 h;
      h.x = f2bf(__expf(xv.x));
      h.y = f2bf(__expf(xv.y));
      h.z = f2bf(__expf(xv.z));
      h.w = f2bf(__expf(xv.w));
      *reinterpret_cast<ushort4*>(&As[b * 64 + (c0 ^ ((b & 7) << 3))]) = h;
    }

    // ---- stage B^T: acc -> bf16 transposed [j][k]; fused column sums.
    // Each thread: k-quad x j-quad. 4 coalesced float4 loads (rows k..k+3 of
    // the same j-quad), rotate write order by r (j&7 spans 8 values across the
    // wave), store ushort4 per column (k..k+3 contiguous after swizzle).
    #pragma unroll
    for (int it = 0; it < 2; ++it) {
      int q   = tid + it * 512;             // 0..1023
      int kp  = q >> 6;                     // 0..15 k-quad
      int jb  = (q & 63) * 4;               // 0..252
      int kl  = kp * 4;                     // local k, multiple of 4
      const float* src = ab + (size_t)(i0 + kl) * NJ + jb;
      float4 v0 = *reinterpret_cast<const float4*>(src);
      float4 v1 = *reinterpret_cast<const float4*>(src + NJ);
      float4 v2 = *reinterpret_cast<const float4*>(src + 2 * NJ);
      float4 v3 = *reinterpret_cast<const float4*>(src + 3 * NJ);
      // rotate each vector left by r: u[c] = v[(c+r)&3]  (no dynamic indexing)
      #define ROT(v, u0, u1, u2, u3)                                            \
        { float t0 = s1 ? v.y : v.x, t1 = s1 ? v.z : v.y,                       \
                t2 = s1 ? v.w : v.z, t3 = s1 ? v.x : v.w;                       \
          u0 = s2 ? t2 : t0; u1 = s2 ? t3 : t1;                                 \
          u2 = s2 ? t0 : t2; u3 = s2 ? t1 : t3; }
      float a00, a01, a02, a03; ROT(v0, a00, a01, a02, a03);
      float a10, a11, a12, a13; ROT(v1, a10, a11, a12, a13);
      float a20, a21, a22, a23; ROT(v2, a20, a21, a22, a23);
      float a30, a31, a32, a33; ROT(v3, a30, a31, a32, a33);
      #undef ROT
      // column cc: jc = jb + ((cc+r)&3); values a0cc..a3cc are k..k+3
      #define STORE_COL(cc, w0, w1, w2, w3)                                     \
        { int jc = jb + ((cc + r) & 3);                                         \
          bsum##cc += w0 + w1 + w2 + w3;                                        \
          ushort4 h; h.x = f2bf(w0); h.y = f2bf(w1);                            \
          h.z = f2bf(w2); h.w = f2bf(w3);                                       \
          *reinterpret_cast<ushort4*>(&Bs[jc * 64 + (kl ^ ((jc & 7) << 3))]) = h; }
      STORE_COL(0, a00, a10, a20, a30);
      STORE_COL(1, a01, a11, a21, a31);
      STORE_COL(2, a02, a12, a22, a32);
      STORE_COL(3, a03, a13, a23, a33);
      #undef STORE_COL
    }
    __syncthreads();

    // ---- MFMA over this K-chunk (2 k-steps of 32)
    #pragma unroll
    for (int ks = 0; ks < 2; ++ks) {
      const int k0 = ks * 32 + 8 * lk;
      bf16x8 af[4], bfr[4];
      #pragma unroll
      for (int m = 0; m < 4; ++m) {
        int row = wr * 64 + m * 16 + l15;
        af[m] = *reinterpret_cast<const bf16x8*>(&As[row * 64 + (k0 ^ ((row & 7) << 3))]);
      }
      #pragma unroll
      for (int n = 0; n < 4; ++n) {
        int row = wc * 64 + n * 16 + l15;
        bfr[n] = *reinterpret_cast<const bf16x8*>(&Bs[row * 64 + (k0 ^ ((row & 7) << 3))]);
      }
      #pragma unroll
      for (int m = 0; m < 4; ++m)
        #pragma unroll
        for (int n = 0; n < 4; ++n)
          C[m][n] = __builtin_amdgcn_mfma_f32_16x16x32_bf16(af[m], bfr[n], C[m][n], 0, 0, 0);
    }
    __syncthreads();
  }

  // ---- reduce per-thread column partials -> logS[j]
  {
    int jb = lane * 4;
    colpart[wid * NJ + jb + ((0 + r) & 3)] = bsum0;
    colpart[wid * NJ + jb + ((1 + r) & 3)] = bsum1;
    colpart[wid * NJ + jb + ((2 + r) & 3)] = bsum2;
    colpart[wid * NJ + jb + ((3 + r) & 3)] = bsum3;
  }
  __syncthreads();
  if (tid < NJ) {
    float s = 0.f;
    #pragma unroll
    for (int c = 0; c < 8; ++c) s += colpart[c * NJ + tid];
    logS[tid] = __logf(s);
  }
  __syncthreads();

  // ---- epilogue: out[b][j] = log(C) - logS[j]
  // C/D layout (16x16): col = lane&15, row = (lane>>4)*4 + reg
  #pragma unroll
  for (int m = 0; m < 4; ++m) {
    int b0 = wr * 64 + m * 16 + lk * 4;
    #pragma unroll
    for (int n = 0; n < 4; ++n) {
      int j = wc * 64 + n * 16 + l15;
      float ls = logS[j];
      #pragma unroll
      for (int rr = 0; rr < 4; ++rr) {
        ob[(size_t)(b0 + rr) * NJ + j] = __logf(C[m][n][rr]) - ls;
      }
    }
  }
}

extern "C" void kernel_launch(void* const* d_in, const int* in_sizes, int n_in,
                              void* d_out, int out_size, void* d_ws, size_t ws_size,
                              hipStream_t stream) {
  const float* x   = (const float*)d_in[0];
  const float* acc = (const float*)d_in[1];
  float* out = (float*)d_out;
  hipLaunchKernelGGL(densesum_kernel, dim3(NSC * NDC * 2), dim3(512), 0, stream, x, acc, out);
}

// Round 4
// 41.696 us; speedup vs baseline: 2.3609x; 2.3609x over previous
//
#include <hip/hip_runtime.h>

// out[s,d,b,j] = log( sum_i exp(x[s,d,b,i]) * acc[s,d,i,j] ) - log( sum_i acc[s,d,i,j] )
// 256 batched 256x256x256 GEMMs in linear space, bf16 MFMA, fp32 accumulate.
// Grid 256 (1 block/CU, traffic-minimal). T14 register prefetch of next K-chunk
// overlaps HBM latency with MFMA + conversion. launch_bounds(512,2): no spills.

#define NB  256
#define NI  256
#define NJ  256

typedef __attribute__((ext_vector_type(8))) short bf16x8;
typedef __attribute__((ext_vector_type(4))) float f32x4;

__device__ __forceinline__ unsigned short f2bf(float f) {
  unsigned int u = __float_as_uint(f);
  u += 0x7FFFu + ((u >> 16) & 1u);
  return (unsigned short)(u >> 16);
}

__global__ __launch_bounds__(512, 2)
void densesum_kernel(const float* __restrict__ x,
                     const float* __restrict__ acc,
                     float* __restrict__ out) {
  const int sd = blockIdx.x;
  const float* xb = x   + (size_t)sd * NB * NI;
  const float* ab = acc + (size_t)sd * NI * NJ;
  float*       ob = out + (size_t)sd * NB * NJ;

  // A = exp(x) [256 b][64 k] bf16 ; B^T = acc^T [256 j][64 k] bf16.
  // 128B rows, XOR swizzle elem ^= ((row&7)<<3) -> conflict-free ds_read_b128.
  __shared__ unsigned short As[NB * 64];
  __shared__ unsigned short Bs[NJ * 64];
  __shared__ float colpart[8 * NJ];
  __shared__ float logS[NJ];

  const int tid  = threadIdx.x;
  const int lane = tid & 63;
  const int wid  = tid >> 6;      // 8 waves
  const int wr   = wid >> 2;      // 0..1  (128-row strip of b)
  const int wc   = wid & 3;       // 0..3  (64-col strip of j)
  const int l15  = lane & 15;
  const int lk   = lane >> 4;     // 0..3
  const int r    = (lane >> 1) & 3;   // B write-order rotation
  const bool s1 = (r & 1), s2 = (r & 2);

  f32x4 C[8][4];
  #pragma unroll
  for (int m = 0; m < 8; ++m)
    #pragma unroll
    for (int n = 0; n < 4; ++n)
      C[m][n] = (f32x4){0.f, 0.f, 0.f, 0.f};

  float bsum0 = 0.f, bsum1 = 0.f, bsum2 = 0.f, bsum3 = 0.f;

  // ---- prefetch registers (T14): chunk = 64 k-cols. A: 8 float4; B: 8 float4.
  float4 pa[8];
  float4 pb[8];   // pb[t*4+rr] = B row kl+rr of task t

  auto loadA = [&](int kc) {
    #pragma unroll
    for (int it = 0; it < 8; ++it) {
      int q  = tid + it * 512;              // 0..4095 quads
      int b  = q >> 4;                      // 0..255
      int c0 = (q & 15) * 4;                // 0..60
      pa[it] = *reinterpret_cast<const float4*>(xb + (size_t)b * NI + kc * 64 + c0);
    }
  };
  auto loadB = [&](int kc) {
    #pragma unroll
    for (int t = 0; t < 2; ++t) {
      int q  = tid + t * 512;               // 0..1023 tasks
      int kl = (q >> 6) * 4;                // 0..60, k-quad
      int jb = (q & 63) * 4;                // 0..252, j-quad
      const float* src = ab + (size_t)(kc * 64 + kl) * NJ + jb;
      pb[t * 4 + 0] = *reinterpret_cast<const float4*>(src);
      pb[t * 4 + 1] = *reinterpret_cast<const float4*>(src + NJ);
      pb[t * 4 + 2] = *reinterpret_cast<const float4*>(src + 2 * NJ);
      pb[t * 4 + 3] = *reinterpret_cast<const float4*>(src + 3 * NJ);
    }
  };
  auto convA = [&]() {
    #pragma unroll
    for (int it = 0; it < 8; ++it) {
      int q  = tid + it * 512;
      int b  = q >> 4;
      int c0 = (q & 15) * 4;
      ushort4 h;
      h.x = f2bf(__expf(pa[it].x));
      h.y = f2bf(__expf(pa[it].y));
      h.z = f2bf(__expf(pa[it].z));
      h.w = f2bf(__expf(pa[it].w));
      *reinterpret_cast<ushort4*>(&As[b * 64 + (c0 ^ ((b & 7) << 3))]) = h;
    }
  };
  auto convB = [&]() {
    #pragma unroll
    for (int t = 0; t < 2; ++t) {
      int q  = tid + t * 512;
      int kl = (q >> 6) * 4;
      int jb = (q & 63) * 4;
      float4 v0 = pb[t * 4 + 0], v1 = pb[t * 4 + 1];
      float4 v2 = pb[t * 4 + 2], v3 = pb[t * 4 + 3];
      // rotate each vector left by r: u[c] = v[(c+r)&3]  (no dynamic indexing)
      #define ROT(v, u0, u1, u2, u3)                                            \
        { float t0 = s1 ? v.y : v.x, t1 = s1 ? v.z : v.y,                       \
                t2 = s1 ? v.w : v.z, t3 = s1 ? v.x : v.w;                       \
          u0 = s2 ? t2 : t0; u1 = s2 ? t3 : t1;                                 \
          u2 = s2 ? t0 : t2; u3 = s2 ? t1 : t3; }
      float a00, a01, a02, a03; ROT(v0, a00, a01, a02, a03);
      float a10, a11, a12, a13; ROT(v1, a10, a11, a12, a13);
      float a20, a21, a22, a23; ROT(v2, a20, a21, a22, a23);
      float a30, a31, a32, a33; ROT(v3, a30, a31, a32, a33);
      #undef ROT
      // column cc: jc = jb + ((cc+r)&3); k-quad contiguous after swizzle (kl%4==0)
      #define STORE_COL(cc, w0, w1, w2, w3)                                     \
        { int jc = jb + ((cc + r) & 3);                                         \
          bsum##cc += w0 + w1 + w2 + w3;                                        \
          ushort4 h; h.x = f2bf(w0); h.y = f2bf(w1);                            \
          h.z = f2bf(w2); h.w = f2bf(w3);                                       \
          *reinterpret_cast<ushort4*>(&Bs[jc * 64 + (kl ^ ((jc & 7) << 3))]) = h; }
      STORE_COL(0, a00, a10, a20, a30);
      STORE_COL(1, a01, a11, a21, a31);
      STORE_COL(2, a02, a12, a22, a32);
      STORE_COL(3, a03, a13, a23, a33);
      #undef STORE_COL
    }
  };

  // ---- pipelined K-loop: conv(kc) -> sync -> issue loads(kc+1) -> MFMA(kc) -> sync
  loadA(0);
  loadB(0);
  for (int kc = 0; kc < 4; ++kc) {
    convA();
    convB();
    __syncthreads();
    if (kc < 3) {           // loads fly across the MFMA phase and the barrier
      loadA(kc + 1);
      loadB(kc + 1);
    }
    #pragma unroll
    for (int ks = 0; ks < 2; ++ks) {
      const int k0 = ks * 32 + 8 * lk;
      bf16x8 bfr[4];
      #pragma unroll
      for (int n = 0; n < 4; ++n) {
        int row = wc * 64 + n * 16 + l15;
        bfr[n] = *reinterpret_cast<const bf16x8*>(&Bs[row * 64 + (k0 ^ ((row & 7) << 3))]);
      }
      #pragma unroll
      for (int m = 0; m < 8; ++m) {
        int row = wr * 128 + m * 16 + l15;
        bf16x8 af = *reinterpret_cast<const bf16x8*>(&As[row * 64 + (k0 ^ ((row & 7) << 3))]);
        #pragma unroll
        for (int n = 0; n < 4; ++n)
          C[m][n] = __builtin_amdgcn_mfma_f32_16x16x32_bf16(af, bfr[n], C[m][n], 0, 0, 0);
      }
    }
    __syncthreads();
  }

  // ---- reduce per-thread column partials -> logS[j]
  {
    int jb = lane * 4;
    colpart[wid * NJ + jb + ((0 + r) & 3)] = bsum0;
    colpart[wid * NJ + jb + ((1 + r) & 3)] = bsum1;
    colpart[wid * NJ + jb + ((2 + r) & 3)] = bsum2;
    colpart[wid * NJ + jb + ((3 + r) & 3)] = bsum3;
  }
  __syncthreads();
  if (tid < NJ) {
    float s = 0.f;
    #pragma unroll
    for (int c = 0; c < 8; ++c) s += colpart[c * NJ + tid];
    logS[tid] = __logf(s);
  }
  __syncthreads();

  // ---- epilogue: out[b][j] = log(C) - logS[j]
  // C/D layout (16x16): col = lane&15, row = (lane>>4)*4 + reg
  #pragma unroll
  for (int m = 0; m < 8; ++m) {
    int b0 = wr * 128 + m * 16 + lk * 4;
    #pragma unroll
    for (int n = 0; n < 4; ++n) {
      int j = wc * 64 + n * 16 + l15;
      float ls = logS[j];
      #pragma unroll
      for (int rr = 0; rr < 4; ++rr) {
        ob[(size_t)(b0 + rr) * NJ + j] = __logf(C[m][n][rr]) - ls;
      }
    }
  }
}

extern "C" void kernel_launch(void* const* d_in, const int* in_sizes, int n_in,
                              void* d_out, int out_size, void* d_ws, size_t ws_size,
                              hipStream_t stream) {
  const float* x   = (const float*)d_in[0];
  const float* acc = (const float*)d_in[1];
  float* out = (float*)d_out;
  hipLaunchKernelGGL(densesum_kernel, dim3(256), dim3(512), 0, stream, x, acc, out);
}

// Round 5
// 38.251 us; speedup vs baseline: 2.5735x; 1.0900x over previous
//
#include <hip/hip_runtime.h>

// out[s,d,b,j] = log( sum_i exp(x[s,d,b,i]) * acc[s,d,i,j] ) - log( sum_i acc[s,d,i,j] )
// 256 batched 256x256x256 GEMMs in linear space, bf16 MFMA, fp32 accumulate.
// Grid 256 (1 block/CU, traffic-minimal). Two-pass persistent-B: B^T bf16 for ALL K
// lives in LDS (128 KB); pass 1 computes b-rows 0..127 while staging B, pass 2
// computes rows 128..255 against resident B (A-only loads). Epilogue-1 writes
// overlap pass-2 loads; final write tail is halved.

#define NB  256
#define NI  256
#define NJ  256
#define BH  128

typedef __attribute__((ext_vector_type(8))) short bf16x8;
typedef __attribute__((ext_vector_type(4))) float f32x4;

__device__ __forceinline__ unsigned short f2bf(float f) {
  unsigned int u = __float_as_uint(f);
  u += 0x7FFFu + ((u >> 16) & 1u);
  return (unsigned short)(u >> 16);
}

__global__ __launch_bounds__(512, 2)
void densesum_kernel(const float* __restrict__ x,
                     const float* __restrict__ acc,
                     float* __restrict__ out) {
  const int sd = blockIdx.x;
  const float* xb = x   + (size_t)sd * NB * NI;
  const float* ab = acc + (size_t)sd * NI * NJ;
  float*       ob = out + (size_t)sd * NB * NJ;

  // As: per-pass A half [128 b][64 k] bf16 (16 KB), 128B rows, swizzle (b&7)<<3.
  // Bs: persistent B^T [256 j][256 k] bf16 (128 KB), 512B rows, swizzle (j&7)<<3
  //     (j*128 dwords == 0 mod 32, so bank pattern identical to the 128B-row case).
  __shared__ unsigned short As[BH * 64];
  __shared__ unsigned short Bs[NJ * NI];
  __shared__ float colpart[8 * NJ];
  __shared__ float logS[NJ];

  const int tid  = threadIdx.x;
  const int lane = tid & 63;
  const int wid  = tid >> 6;      // 8 waves
  const int wr   = wid >> 2;      // 0..1  (64-row strip of local b)
  const int wc   = wid & 3;       // 0..3  (64-col strip of j)
  const int l15  = lane & 15;
  const int lk   = lane >> 4;     // 0..3
  const int r    = (lane >> 1) & 3;   // B write-order rotation
  const bool s1 = (r & 1), s2 = (r & 2);

  f32x4 C[4][4];
  float bsum0 = 0.f, bsum1 = 0.f, bsum2 = 0.f, bsum3 = 0.f;
  float4 pa[4];   // A prefetch: 4 float4 / thread / chunk (128 rows x 64 k)
  float4 pb[8];   // B prefetch: 8 float4 / thread / chunk (64 k x 256 j)

  auto zeroC = [&]() {
    #pragma unroll
    for (int m = 0; m < 4; ++m)
      #pragma unroll
      for (int n = 0; n < 4; ++n)
        C[m][n] = (f32x4){0.f, 0.f, 0.f, 0.f};
  };

  auto loadA = [&](const float* xh, int kc) {
    #pragma unroll
    for (int it = 0; it < 4; ++it) {
      int q  = tid + it * 512;              // 0..2047 quads
      int b  = q >> 4;                      // 0..127
      int c0 = (q & 15) * 4;                // 0..60
      pa[it] = *reinterpret_cast<const float4*>(xh + (size_t)b * NI + kc * 64 + c0);
    }
  };
  auto loadB = [&](int kc) {
    #pragma unroll
    for (int t = 0; t < 2; ++t) {
      int q  = tid + t * 512;               // 0..1023 tasks
      int kl = (q >> 6) * 4;                // 0..60, k-quad
      int jb = (q & 63) * 4;                // 0..252, j-quad
      const float* src = ab + (size_t)(kc * 64 + kl) * NJ + jb;
      pb[t * 4 + 0] = *reinterpret_cast<const float4*>(src);
      pb[t * 4 + 1] = *reinterpret_cast<const float4*>(src + NJ);
      pb[t * 4 + 2] = *reinterpret_cast<const float4*>(src + 2 * NJ);
      pb[t * 4 + 3] = *reinterpret_cast<const float4*>(src + 3 * NJ);
    }
  };
  auto convA = [&]() {
    #pragma unroll
    for (int it = 0; it < 4; ++it) {
      int q  = tid + it * 512;
      int b  = q >> 4;
      int c0 = (q & 15) * 4;
      ushort4 h;
      h.x = f2bf(__expf(pa[it].x));
      h.y = f2bf(__expf(pa[it].y));
      h.z = f2bf(__expf(pa[it].z));
      h.w = f2bf(__expf(pa[it].w));
      *reinterpret_cast<ushort4*>(&As[b * 64 + (c0 ^ ((b & 7) << 3))]) = h;
    }
  };
  auto convB = [&](int kc) {
    #pragma unroll
    for (int t = 0; t < 2; ++t) {
      int q   = tid + t * 512;
      int kl  = (q >> 6) * 4;
      int jb  = (q & 63) * 4;
      int kg  = kc * 64 + kl;               // global k, multiple of 4
      float4 v0 = pb[t * 4 + 0], v1 = pb[t * 4 + 1];
      float4 v2 = pb[t * 4 + 2], v3 = pb[t * 4 + 3];
      // rotate each vector left by r: u[c] = v[(c+r)&3]  (no dynamic indexing)
      #define ROT(v, u0, u1, u2, u3)                                            \
        { float t0 = s1 ? v.y : v.x, t1 = s1 ? v.z : v.y,                       \
                t2 = s1 ? v.w : v.z, t3 = s1 ? v.x : v.w;                       \
          u0 = s2 ? t2 : t0; u1 = s2 ? t3 : t1;                                 \
          u2 = s2 ? t0 : t2; u3 = s2 ? t1 : t3; }
      float a00, a01, a02, a03; ROT(v0, a00, a01, a02, a03);
      float a10, a11, a12, a13; ROT(v1, a10, a11, a12, a13);
      float a20, a21, a22, a23; ROT(v2, a20, a21, a22, a23);
      float a30, a31, a32, a33; ROT(v3, a30, a31, a32, a33);
      #undef ROT
      // column cc: jc = jb + ((cc+r)&3); k-quad contiguous after swizzle (kg%4==0)
      #define STORE_COL(cc, w0, w1, w2, w3)                                     \
        { int jc = jb + ((cc + r) & 3);                                         \
          bsum##cc += w0 + w1 + w2 + w3;                                        \
          ushort4 h; h.x = f2bf(w0); h.y = f2bf(w1);                            \
          h.z = f2bf(w2); h.w = f2bf(w3);                                       \
          *reinterpret_cast<ushort4*>(&Bs[jc * NI + (kg ^ ((jc & 7) << 3))]) = h; }
      STORE_COL(0, a00, a10, a20, a30);
      STORE_COL(1, a01, a11, a21, a31);
      STORE_COL(2, a02, a12, a22, a32);
      STORE_COL(3, a03, a13, a23, a33);
      #undef STORE_COL
    }
  };
  auto mfmaChunk = [&](int kc) {
    #pragma unroll
    for (int ks = 0; ks < 2; ++ks) {
      const int ka = ks * 32 + 8 * lk;            // k within As (64-col rows)
      const int kg = kc * 64 + ka;                // k within Bs (256-col rows)
      bf16x8 bfr[4];
      #pragma unroll
      for (int n = 0; n < 4; ++n) {
        int row = wc * 64 + n * 16 + l15;
        bfr[n] = *reinterpret_cast<const bf16x8*>(&Bs[row * NI + (kg ^ ((row & 7) << 3))]);
      }
      #pragma unroll
      for (int m = 0; m < 4; ++m) {
        int row = wr * 64 + m * 16 + l15;
        bf16x8 af = *reinterpret_cast<const bf16x8*>(&As[row * 64 + (ka ^ ((row & 7) << 3))]);
        #pragma unroll
        for (int n = 0; n < 4; ++n)
          C[m][n] = __builtin_amdgcn_mfma_f32_16x16x32_bf16(af, bfr[n], C[m][n], 0, 0, 0);
      }
    }
  };
  auto epilogue = [&](int bh) {
    float* obh = ob + (size_t)bh * BH * NJ;
    #pragma unroll
    for (int m = 0; m < 4; ++m) {
      int b0 = wr * 64 + m * 16 + lk * 4;
      #pragma unroll
      for (int n = 0; n < 4; ++n) {
        int j = wc * 64 + n * 16 + l15;
        float ls = logS[j];
        #pragma unroll
        for (int rr = 0; rr < 4; ++rr) {
          obh[(size_t)(b0 + rr) * NJ + j] = __logf(C[m][n][rr]) - ls;
        }
      }
    }
  };

  // ================= pass 1: b-rows 0..127, stage B persistently =================
  loadA(xb, 0);
  loadB(0);
  zeroC();
  for (int kc = 0; kc < 4; ++kc) {
    convA();
    convB(kc);
    __syncthreads();
    if (kc < 3) {            // loads fly across the MFMA phase and the barrier
      loadA(xb, kc + 1);
      loadB(kc + 1);
    } else {                 // prefetch pass-2 chunk 0 (A only)
      loadA(xb + (size_t)BH * NI, 0);
    }
    mfmaChunk(kc);
    __syncthreads();
  }

  // ---- column sums -> logS[j] (B was staged exactly once)
  {
    int jb = lane * 4;
    colpart[wid * NJ + jb + ((0 + r) & 3)] = bsum0;
    colpart[wid * NJ + jb + ((1 + r) & 3)] = bsum1;
    colpart[wid * NJ + jb + ((2 + r) & 3)] = bsum2;
    colpart[wid * NJ + jb + ((3 + r) & 3)] = bsum3;
  }
  __syncthreads();
  if (tid < NJ) {
    float s = 0.f;
    #pragma unroll
    for (int c = 0; c < 8; ++c) s += colpart[c * NJ + tid];
    logS[tid] = __logf(s);
  }
  __syncthreads();

  // ---- epilogue half 0 (overlaps pass-2 chunk-0 loads already in flight)
  epilogue(0);

  // ================= pass 2: b-rows 128..255 against resident Bs =================
  zeroC();
  for (int kc = 0; kc < 4; ++kc) {
    convA();
    __syncthreads();
    if (kc < 3) loadA(xb + (size_t)BH * NI, kc + 1);
    mfmaChunk(kc);
    __syncthreads();
  }

  epilogue(1);
}

extern "C" void kernel_launch(void* const* d_in, const int* in_sizes, int n_in,
                              void* d_out, int out_size, void* d_ws, size_t ws_size,
                              hipStream_t stream) {
  const float* x   = (const float*)d_in[0];
  const float* acc = (const float*)d_in[1];
  float* out = (float*)d_out;
  hipLaunchKernelGGL(densesum_kernel, dim3(256), dim3(512), 0, stream, x, acc, out);
}